// Round 4
// baseline (1932.896 us; speedup 1.0000x reference)
//
#include <hip/hip_runtime.h>
#include <type_traits>

#define DD 12
#define VOX 1728
#define BN_EPS 1e-5f
#define BATCH 512
#define PER 864
#define PERZ 865                                  // PER + 1 zero row per batch

typedef __attribute__((ext_vector_type(8))) short short8;   // 8 bf16 = 16B
typedef __attribute__((ext_vector_type(4))) float f32x4;
typedef unsigned short u16;

__device__ inline u16 f2b(float f) {              // fp32 -> bf16 RNE
    union { float f; unsigned u; } v; v.f = f;
    unsigned r = v.u + 0x7fffu + ((v.u >> 16) & 1u);
    return (u16)(r >> 16);
}
__device__ inline float b2f(u16 h) {
    union { unsigned u; float f; } v; v.u = ((unsigned)h) << 16;
    return v.f;
}
constexpr int ilog2(int v) { return v == 1 ? 0 : 1 + ilog2(v / 2); }

__device__ __forceinline__ void async_copy16(const void* g, void* l) {
    __builtin_amdgcn_global_load_lds(
        (const __attribute__((address_space(1))) void*)g,
        (__attribute__((address_space(3))) void*)l, 16, 0, 0);
}

// ---------------- voxel -> point-row map ----------------
__global__ void build_map_kernel(const int* __restrict__ idx, int* __restrict__ map, int N) {
    int p = blockIdx.x * blockDim.x + threadIdx.x;
    if (p >= N) return;
    const int4 v = ((const int4*)idx)[p];
    map[v.x * VOX + (v.y * DD + v.z) * DD + v.w] = p;
}

// ---------------- neighbor table: local row in batch, PER = zero-row sentinel ----------------
__global__ void build_nbr_kernel(const int* __restrict__ idx, const int* __restrict__ map,
                                 u16* __restrict__ nbr, int N) {
    int t = blockIdx.x * blockDim.x + threadIdx.x;
    int p = t >> 5, nk = t & 31;
    if (p >= N) return;
    u16 out = PER;
    if (nk < 27) {
        const int4 v = ((const int4*)idx)[p];
        int dz = nk / 9 - 1, dy = (nk / 3) % 3 - 1, dx = nk % 3 - 1;
        int zz = v.y + dz, yy = v.z + dy, xx = v.w + dx;
        if (zz >= 0 && zz < DD && yy >= 0 && yy < DD && xx >= 0 && xx < DD) {
            int q = map[v.x * VOX + (zz * DD + yy) * DD + xx];
            if (q >= 0) out = (u16)(q - v.x * PER);
        }
    }
    nbr[t] = out;
}

// ---------------- W [K][COUT] fp32 -> Wt [COUT][Kpad] bf16 (pad pre-zeroed) ----------------
__global__ void transpose_w_kernel(const float* __restrict__ W, u16* __restrict__ Wt,
                                   int K, int COUT, int Kpad) {
    int i = blockIdx.x * blockDim.x + threadIdx.x;
    if (i >= K * COUT) return;
    int n = i % COUT, k = i / COUT;
    Wt[(size_t)n * Kpad + k] = f2b(W[i]);
}

// ---------------- zero the per-batch zero rows of a feature buffer ----------------
__global__ void zero_rows_kernel(u16* __restrict__ f, int CIN) {
    int t = blockIdx.x * blockDim.x + threadIdx.x;          // over BATCH*CIN/4
    int e4 = CIN >> 2;
    if (t >= BATCH * e4) return;
    int b = t / e4, k = t - b * e4;
    ((ushort4*)f)[(size_t)(b * PERZ + PER) * e4 + k] = make_ushort4(0, 0, 0, 0);
}

// ---------------- fp32 feats -> bf16, strided (PERZ) layout ----------------
__global__ void cast_bf16_kernel(const float* __restrict__ in, u16* __restrict__ out, int N4) {
    int i = blockIdx.x * blockDim.x + threadIdx.x;          // over N*4 (float4 groups, CIN=16)
    if (i >= N4) return;
    float4 v = ((const float4*)in)[i];
    int p = i >> 2, c4 = i & 3;
    int b = p / PER, r = p - b * PER;
    ushort4 o;
    o.x = f2b(v.x); o.y = f2b(v.y); o.z = f2b(v.z); o.w = f2b(v.w);
    ((ushort4*)out)[(size_t)(b * PERZ + r) * 4 + c4] = o;
}

// ---------------- implicit-GEMM conv: async-DMA dbuf K-loop, one barrier/step ----------------
// y[N][COUT] += bias ; fused per-channel sum/sumsq -> stats
// Block: 128 rows x 64 cols, 4 waves (wave tile 32x64). blockIdx.y = 64-col tile.
template<int CIN, int COUT>
__global__ __launch_bounds__(256) void conv_mfma_kernel(
    const u16* __restrict__ fin,      // (BATCH*PERZ) x CIN bf16 (zero row per batch)
    const u16* __restrict__ nbr,      // N x 32 u16
    const u16* __restrict__ Wt,       // COUT x Kpad bf16
    const float* __restrict__ bias,
    float* __restrict__ y,
    float* __restrict__ stats) {
    constexpr int Kpad   = (27 * CIN + 63) & ~63;
    constexpr int KSTEPS = Kpad / 64;
    constexpr int L2C    = ilog2(CIN);
    // LDS layout (48 KB): B0 @0 (8K), B1 @8K, A0 @16K (16K), A1 @32K
    __shared__ char smem[49152];

    // XCD-contiguous swizzle
    const int perx = gridDim.x >> 3;
    const int bid = (blockIdx.x & 7) * perx + (blockIdx.x >> 3);
    const int p0 = bid * 128;
    const int col0 = blockIdx.y * 64;

    const int tid = threadIdx.x;
    const int wave = tid >> 6, lane = tid & 63;
    const int lq = lane >> 4, lr = lane & 15;
    const int lrow = lane >> 3;                   // DMA row-within-slot
    const int kc_d = (lane & 7) ^ (lrow & 7);     // swizzled chunk this lane fetches

    // ---- per-slot invariants ----
    // A slots i<4: rows m = (wave*4+i)*8 + lrow
    int qvoff[4], gbase[4];
    #pragma unroll
    for (int i = 0; i < 4; i++) {
        int m = (wave * 4 + i) * 8 + lrow;
        int p = p0 + m;
        int b = p / PER;
        qvoff[i] = p * 64 + (((kc_d * 8) >> L2C) * 2);          // bytes into nbr
        gbase[i] = b * PERZ * CIN + ((kc_d * 8) & (CIN - 1));   // elems into fin
    }
    // B slots j<2: rows n = col0 + (wave*2+j)*8 + lrow
    int bvoff[2];
    #pragma unroll
    for (int j = 0; j < 2; j++)
        bvoff[j] = (col0 + (wave * 2 + j) * 8 + lrow) * Kpad + kc_d * 8;

    // fragment read addrs (physical chunk = logical ^ (row&7))
    int vA[2], vB[2];
    #pragma unroll
    for (int s = 0; s < 2; s++) {
        int phys = ((s * 4 + lq) ^ (lr & 7)) * 16;
        vA[s] = (wave * 32 + lr) * 128 + phys;
        vB[s] = lr * 128 + phys;
    }

    const f32x4 fzero = {0.f, 0.f, 0.f, 0.f};
    f32x4 acc[2][4];
    #pragma unroll
    for (int i = 0; i < 2; i++)
        #pragma unroll
        for (int j = 0; j < 4; j++) acc[i][j] = fzero;

    u16 qe[4], qo[4];
    auto loadQ = [&](int step, u16* qd) {
        int sQ = ((step * 64) >> L2C) * 2;
        #pragma unroll
        for (int i = 0; i < 4; i++)
            qd[i] = *(const u16*)((const char*)nbr + (qvoff[i] + sQ));
    };
    auto stage = [&](int step, int buf, const u16* q) {
        int sG = (step * 64) & (CIN - 1);
        const u16* fs = fin + sG;
        #pragma unroll
        for (int i = 0; i < 4; i++) {
            const u16* src = fs + gbase[i] + ((int)q[i] << L2C);
            char* lds = smem + 16384 + buf * 16384 + (wave * 4 + i) * 1024;
            async_copy16(src, lds);
        }
        const u16* wsrc = Wt + step * 64;
        #pragma unroll
        for (int j = 0; j < 2; j++) {
            const u16* src = wsrc + bvoff[j];
            char* lds = smem + buf * 8192 + (wave * 2 + j) * 1024;
            async_copy16(src, lds);
        }
    };
    auto domfma = [&](auto BUF) {
        constexpr int buf = decltype(BUF)::value;
        #pragma unroll
        for (int s = 0; s < 2; s++) {
            short8 af[2], bfr[4];
            #pragma unroll
            for (int i = 0; i < 2; i++)
                af[i] = *(const short8*)(smem + 16384 + buf * 16384 + i * 2048 + vA[s]);
            #pragma unroll
            for (int j = 0; j < 4; j++)
                bfr[j] = *(const short8*)(smem + buf * 8192 + j * 2048 + vB[s]);
            #pragma unroll
            for (int i = 0; i < 2; i++)
                #pragma unroll
                for (int j = 0; j < 4; j++)
                    acc[i][j] = __builtin_amdgcn_mfma_f32_16x16x32_bf16(af[i], bfr[j], acc[i][j], 0, 0, 0);
        }
    };

    // ---- prologue ----
    loadQ(0, qe);
    stage(0, 0, qe);
    loadQ(1, qo);

    // ---- main loop: one barrier per K-step, DMA k+1 hidden under MFMA k ----
    #pragma unroll 1
    for (int kb = 0; kb < KSTEPS; kb += 2) {
        __syncthreads();                           // drains DMA(kb) -> buf0
        if (kb + 1 < KSTEPS) stage(kb + 1, 1, qo);
        loadQ(kb + 2, qe);
        domfma(std::integral_constant<int, 0>{});
        __syncthreads();                           // drains DMA(kb+1) -> buf1
        if (kb + 2 < KSTEPS) stage(kb + 2, 0, qe);
        loadQ(kb + 3, qo);
        if (kb + 1 < KSTEPS) domfma(std::integral_constant<int, 1>{});
    }

    // ---- epilogue: bias, store y, fused per-channel sum/sumsq ----
    #pragma unroll
    for (int j = 0; j < 4; j++) {
        int col = col0 + j * 16 + lr;
        float bv = bias[col];
        float s = 0.f, s2 = 0.f;
        #pragma unroll
        for (int i = 0; i < 2; i++) {
            int row0 = p0 + wave * 32 + i * 16 + lq * 4;
            #pragma unroll
            for (int r = 0; r < 4; r++) {
                float v = acc[i][j][r] + bv;
                y[(size_t)(row0 + r) * COUT + col] = v;
                s += v; s2 += v * v;
            }
        }
        s  += __shfl_down(s, 32);  s  += __shfl_down(s, 16);
        s2 += __shfl_down(s2, 32); s2 += __shfl_down(s2, 16);
        if (lane < 16) {
            atomicAdd(&stats[col], s);
            atomicAdd(&stats[COUT + col], s2);
        }
    }
}

// ---------------- fold BN into scale/shift ----------------
template<int COUT>
__global__ void finalize_kernel(const float* __restrict__ stats, const float* __restrict__ gamma,
                                const float* __restrict__ beta, float* __restrict__ ss, int N) {
    int co = threadIdx.x;
    float inv_n = 1.f / (float)N;
    float mu  = stats[co] * inv_n;
    float var = stats[COUT + co] * inv_n - mu * mu;
    float sc  = gamma[co] * rsqrtf(var + BN_EPS);
    ss[co]        = sc;
    ss[COUT + co] = beta[co] - mu * sc;
}

// ---------------- BN + ReLU, emit bf16 into strided (PERZ) layout ----------------
template<int COUT>
__global__ void apply_kernel(const float* __restrict__ y, const float* __restrict__ ss,
                             u16* __restrict__ f, int total4) {
    int i = blockIdx.x * blockDim.x + threadIdx.x;
    if (i >= total4) return;
    constexpr int E4 = COUT / 4;
    float4 v = ((const float4*)y)[i];
    int p = i / E4, k = i - p * E4;
    int c0 = k * 4;
    int b = p / PER, r = p - b * PER;
    ushort4 o;
    float a;
    a = fmaf(v.x, ss[c0 + 0], ss[COUT + c0 + 0]); o.x = f2b(a > 0.f ? a : 0.f);
    a = fmaf(v.y, ss[c0 + 1], ss[COUT + c0 + 1]); o.y = f2b(a > 0.f ? a : 0.f);
    a = fmaf(v.z, ss[c0 + 2], ss[COUT + c0 + 2]); o.z = f2b(a > 0.f ? a : 0.f);
    a = fmaf(v.w, ss[c0 + 3], ss[COUT + c0 + 3]); o.w = f2b(a > 0.f ? a : 0.f);
    ((ushort4*)f)[(size_t)(b * PERZ + r) * E4 + k] = o;
}

// ---------------- dense NCDHW output ----------------
__global__ void output_kernel(const u16* __restrict__ f, const int* __restrict__ map,
                              float* __restrict__ out, int total) {
    int i = blockIdx.x * blockDim.x + threadIdx.x;
    if (i >= total) return;
    int voxel = i % VOX;
    int bc    = i / VOX;
    int c = bc & 63;
    int b = bc >> 6;
    int p = map[b * VOX + voxel];
    float v = 0.f;
    if (p >= 0) {
        int r = p - b * PER;
        v = b2f(f[(size_t)(b * PERZ + r) * 64 + c]);
    }
    out[i] = v;
}

extern "C" void kernel_launch(void* const* d_in, const int* in_sizes, int n_in,
                              void* d_out, int out_size, void* d_ws, size_t ws_size,
                              hipStream_t stream) {
    const float* feats = (const float*)d_in[0];
    const int*   idx   = (const int*)  d_in[1];
    const float* W0 = (const float*)d_in[3];
    const float* b0 = (const float*)d_in[4];
    const float* g0 = (const float*)d_in[5];
    const float* e0 = (const float*)d_in[6];
    const float* W1 = (const float*)d_in[7];
    const float* b1 = (const float*)d_in[8];
    const float* g1 = (const float*)d_in[9];
    const float* e1 = (const float*)d_in[10];
    const float* W2 = (const float*)d_in[11];
    const float* b2 = (const float*)d_in[12];
    const float* g2 = (const float*)d_in[13];
    const float* e2 = (const float*)d_in[14];

    const int N = in_sizes[0] / 16;               // 442368

    // ---- workspace layout ----
    char* ws = (char*)d_ws;
    size_t off = 0;
    auto alloc = [&](size_t bytes) { void* p = ws + off; off = (off + bytes + 255) & ~(size_t)255; return p; };
    int*   map   = (int*)  alloc((size_t)BATCH * VOX * 4);
    float* stats = (float*)alloc(3 * 256 * 4);
    float* ss    = (float*)alloc(3 * 256 * 4);
    u16*   nbr   = (u16*)  alloc((size_t)N * 32 * 2);
    u16*   wt0   = (u16*)  alloc((size_t)64  * 448  * 2);
    u16*   wt1   = (u16*)  alloc((size_t)128 * 1728 * 2);
    u16*   wt2   = (u16*)  alloc((size_t)64  * 3456 * 2);
    u16*   fbuf  = (u16*)  alloc((size_t)BATCH * PERZ * 128 * 2);   // shared by all layers (time-disjoint)
    float* y = (float*)d_out;                     // fp32 conv out, aliases d_out

    hipMemsetAsync(map,   0xFF, (size_t)BATCH * VOX * 4, stream);
    hipMemsetAsync(stats, 0,    3 * 256 * 4, stream);
    hipMemsetAsync(wt0,   0,    (size_t)64 * 448 * 2, stream);      // zero K-pad
    build_map_kernel<<<(N + 255) / 256, 256, 0, stream>>>(idx, map, N);
    build_nbr_kernel<<<(N * 32 + 255) / 256, 256, 0, stream>>>(idx, map, nbr, N);
    transpose_w_kernel<<<(432  * 64  + 255) / 256, 256, 0, stream>>>(W0, wt0, 432,  64,  448);
    transpose_w_kernel<<<(1728 * 128 + 255) / 256, 256, 0, stream>>>(W1, wt1, 1728, 128, 1728);
    transpose_w_kernel<<<(3456 * 64  + 255) / 256, 256, 0, stream>>>(W2, wt2, 3456, 64,  3456);

    const int NB = N / 128;                       // 3456 row-tiles (div by 8 for swizzle)

    // ---- layer 1: 16 -> 64 ----
    zero_rows_kernel<<<(BATCH * 4 + 255) / 256, 256, 0, stream>>>(fbuf, 16);
    cast_bf16_kernel<<<(N * 4 + 255) / 256, 256, 0, stream>>>(feats, fbuf, N * 4);
    conv_mfma_kernel<16, 64><<<dim3(NB, 1), 256, 0, stream>>>(fbuf, nbr, wt0, b0, y, stats + 0);
    finalize_kernel<64><<<1, 64, 0, stream>>>(stats + 0, g0, e0, ss + 0, N);
    zero_rows_kernel<<<(BATCH * 16 + 255) / 256, 256, 0, stream>>>(fbuf, 64);
    apply_kernel<64><<<(N * 16 + 255) / 256, 256, 0, stream>>>(y, ss + 0, fbuf, N * 16);

    // ---- layer 2: 64 -> 128 ----
    conv_mfma_kernel<64, 128><<<dim3(NB, 2), 256, 0, stream>>>(fbuf, nbr, wt1, b1, y, stats + 256);
    finalize_kernel<128><<<1, 128, 0, stream>>>(stats + 256, g1, e1, ss + 256, N);
    zero_rows_kernel<<<(BATCH * 32 + 255) / 256, 256, 0, stream>>>(fbuf, 128);
    apply_kernel<128><<<(N * 32 + 255) / 256, 256, 0, stream>>>(y, ss + 256, fbuf, N * 32);

    // ---- layer 3: 128 -> 64 ----
    conv_mfma_kernel<128, 64><<<dim3(NB, 1), 256, 0, stream>>>(fbuf, nbr, wt2, b2, y, stats + 512);
    finalize_kernel<64><<<1, 64, 0, stream>>>(stats + 512, g2, e2, ss + 512, N);
    zero_rows_kernel<<<(BATCH * 16 + 255) / 256, 256, 0, stream>>>(fbuf, 64);
    apply_kernel<64><<<(N * 16 + 255) / 256, 256, 0, stream>>>(y, ss + 512, fbuf, N * 16);

    // ---- dense NCDHW output ----
    output_kernel<<<(out_size + 255) / 256, 256, 0, stream>>>(fbuf, map, (float*)d_out, out_size);
}

// Round 5
// 1494.324 us; speedup vs baseline: 1.2935x; 1.2935x over previous
//
#include <hip/hip_runtime.h>

#define DD 12
#define VOX 1728
#define BN_EPS 1e-5f
#define BATCH 512
#define PER 864
#define PERZ 865                                  // PER + 1 zero row per batch

typedef __attribute__((ext_vector_type(8))) short short8;   // 8 bf16 = 16B
typedef __attribute__((ext_vector_type(4))) float f32x4;
typedef unsigned short u16;

__device__ inline u16 f2b(float f) {              // fp32 -> bf16 RNE
    union { float f; unsigned u; } v; v.f = f;
    unsigned r = v.u + 0x7fffu + ((v.u >> 16) & 1u);
    return (u16)(r >> 16);
}
__device__ inline float b2f(u16 h) {
    union { unsigned u; float f; } v; v.u = ((unsigned)h) << 16;
    return v.f;
}
constexpr int ilog2(int v) { return v == 1 ? 0 : 1 + ilog2(v / 2); }

__device__ __forceinline__ void async_copy16(const void* g, void* l) {
    __builtin_amdgcn_global_load_lds(
        (const __attribute__((address_space(1))) void*)g,
        (__attribute__((address_space(3))) void*)l, 16, 0, 0);
}

// ---------------- voxel -> point-row map ----------------
__global__ void build_map_kernel(const int* __restrict__ idx, int* __restrict__ map, int N) {
    int p = blockIdx.x * blockDim.x + threadIdx.x;
    if (p >= N) return;
    const int4 v = ((const int4*)idx)[p];
    map[v.x * VOX + (v.y * DD + v.z) * DD + v.w] = p;
}

// ---------------- neighbor table: local row in batch, PER = zero-row sentinel ----------------
__global__ void build_nbr_kernel(const int* __restrict__ idx, const int* __restrict__ map,
                                 u16* __restrict__ nbr, int N) {
    int t = blockIdx.x * blockDim.x + threadIdx.x;
    int p = t >> 5, nk = t & 31;
    if (p >= N) return;
    u16 out = PER;
    if (nk < 27) {
        const int4 v = ((const int4*)idx)[p];
        int dz = nk / 9 - 1, dy = (nk / 3) % 3 - 1, dx = nk % 3 - 1;
        int zz = v.y + dz, yy = v.z + dy, xx = v.w + dx;
        if (zz >= 0 && zz < DD && yy >= 0 && yy < DD && xx >= 0 && xx < DD) {
            int q = map[v.x * VOX + (zz * DD + yy) * DD + xx];
            if (q >= 0) out = (u16)(q - v.x * PER);
        }
    }
    nbr[t] = out;
}

// ---------------- W [K][COUT] fp32 -> Wt [COUT][Kpad] bf16 (pad pre-zeroed) ----------------
__global__ void transpose_w_kernel(const float* __restrict__ W, u16* __restrict__ Wt,
                                   int K, int COUT, int Kpad) {
    int i = blockIdx.x * blockDim.x + threadIdx.x;
    if (i >= K * COUT) return;
    int n = i % COUT, k = i / COUT;
    Wt[(size_t)n * Kpad + k] = f2b(W[i]);
}

// ---------------- zero the per-batch zero rows of a feature buffer ----------------
__global__ void zero_rows_kernel(u16* __restrict__ f, int CIN) {
    int t = blockIdx.x * blockDim.x + threadIdx.x;          // over BATCH*CIN/4
    int e4 = CIN >> 2;
    if (t >= BATCH * e4) return;
    int b = t / e4, k = t - b * e4;
    ((ushort4*)f)[(size_t)(b * PERZ + PER) * e4 + k] = make_ushort4(0, 0, 0, 0);
}

// ---------------- fp32 feats -> bf16, strided (PERZ) layout ----------------
__global__ void cast_bf16_kernel(const float* __restrict__ in, u16* __restrict__ out, int N4) {
    int i = blockIdx.x * blockDim.x + threadIdx.x;          // over N*4 (float4 groups, CIN=16)
    if (i >= N4) return;
    float4 v = ((const float4*)in)[i];
    int p = i >> 2, c4 = i & 3;
    int b = p / PER, r = p - b * PER;
    ushort4 o;
    o.x = f2b(v.x); o.y = f2b(v.y); o.z = f2b(v.z); o.w = f2b(v.w);
    ((ushort4*)out)[(size_t)(b * PERZ + r) * 4 + c4] = o;
}

// ---------------- implicit-GEMM conv: m97-style single-buffer async-DMA K-loop ----------------
// Wave tile 64x64 (acc 4x4), BK=64, 2 barriers/step, global_load_lds staging.
// Block tile BM x (WN*64), WM*WN waves = 4 (256 threads).
template<int CIN, int COUT, int BM, int WM, int WN>
__global__ __launch_bounds__(256) void conv_mfma_kernel(
    const u16* __restrict__ fin,      // (BATCH*PERZ) x CIN bf16 (zero row per batch)
    const u16* __restrict__ nbr,      // N x 32 u16
    const u16* __restrict__ Wt,       // COUT x Kpad bf16
    const float* __restrict__ bias,
    float* __restrict__ y,
    float* __restrict__ stats) {
    constexpr int Kpad   = (27 * CIN + 63) & ~63;
    constexpr int KSTEPS = Kpad / 64;
    constexpr int L2C    = ilog2(CIN);
    constexpr int BN     = WN * 64;
    constexpr int ASLOTS = BM / 32;               // per-thread 16B DMA slots for A
    constexpr int BSLOTS = BN / 32;
    constexpr int A_OFF  = BN * 128;              // sB first, then sA
    __shared__ char smem[(BM + BN) * 128];

    // XCD-contiguous swizzle
    const int perx = gridDim.x >> 3;
    const int bid = (blockIdx.x & 7) * perx + (blockIdx.x >> 3);
    const int p0 = bid * BM;

    const int tid = threadIdx.x;
    const int wave = tid >> 6, lane = tid & 63;
    const int wm = wave / WN, wn = wave % WN;     // 64x64 wave tile at (wm*64, wn*64)
    const int lq = lane >> 4, lr = lane & 15;
    const int lrow = lane >> 3;                   // DMA row within 8-row group
    const int kc_d = (lane & 7) ^ (lrow & 7);     // swizzled chunk this lane fetches

    // ---- per-slot invariants ----
    int qvoff[ASLOTS], gbase[ASLOTS];
    #pragma unroll
    for (int i = 0; i < ASLOTS; i++) {
        int m = (wave * ASLOTS + i) * 8 + lrow;
        int p = p0 + m;
        int b = p / PER;
        qvoff[i] = p * 64 + (((kc_d * 8) >> L2C) * 2);          // bytes into nbr
        gbase[i] = b * PERZ * CIN + ((kc_d * 8) & (CIN - 1));   // elems into fin
    }
    int bvoff[BSLOTS];
    #pragma unroll
    for (int j = 0; j < BSLOTS; j++)
        bvoff[j] = ((wave * BSLOTS + j) * 8 + lrow) * Kpad + kc_d * 8;

    // fragment read addrs: physical chunk = logical ^ (row&7)
    int phs[2];
    phs[0] = ((0 + lq) ^ (lr & 7)) * 16;
    phs[1] = ((4 + lq) ^ (lr & 7)) * 16;
    const int aBase = A_OFF + (wm * 64 + lr) * 128;
    const int bBase = (wn * 64 + lr) * 128;

    const f32x4 fzero = {0.f, 0.f, 0.f, 0.f};
    f32x4 acc[4][4];
    #pragma unroll
    for (int i = 0; i < 4; i++)
        #pragma unroll
        for (int j = 0; j < 4; j++) acc[i][j] = fzero;

    u16 q[ASLOTS];
    auto loadQ = [&](int step) {
        int sQ = ((step * 64) >> L2C) * 2;
        #pragma unroll
        for (int i = 0; i < ASLOTS; i++)
            q[i] = *(const u16*)((const char*)nbr + qvoff[i] + sQ);
    };
    auto stage = [&](int step) {
        int sG = (step * 64) & (CIN - 1);
        const u16* fs = fin + sG;
        #pragma unroll
        for (int i = 0; i < ASLOTS; i++)
            async_copy16(fs + gbase[i] + ((int)q[i] << L2C),
                         smem + A_OFF + (wave * ASLOTS + i) * 1024);
        const u16* wsrc = Wt + step * 64;
        #pragma unroll
        for (int j = 0; j < BSLOTS; j++)
            async_copy16(wsrc + bvoff[j], smem + (wave * BSLOTS + j) * 1024);
    };

    loadQ(0);
    #pragma unroll 1
    for (int kb = 0; kb < KSTEPS; kb++) {
        __syncthreads();                          // all waves done reading previous tile
        stage(kb);                                // async DMA A+B into LDS
        if (kb + 1 < KSTEPS) loadQ(kb + 1);       // prefetch next step's neighbor ids
        __syncthreads();                          // vmcnt(0) drain -> DMA landed
        #pragma unroll
        for (int s = 0; s < 2; s++) {
            short8 af[4], bfr[4];
            #pragma unroll
            for (int i = 0; i < 4; i++)
                af[i] = *(const short8*)(smem + aBase + i * 2048 + phs[s]);
            #pragma unroll
            for (int j = 0; j < 4; j++)
                bfr[j] = *(const short8*)(smem + bBase + j * 2048 + phs[s]);
            #pragma unroll
            for (int i = 0; i < 4; i++)
                #pragma unroll
                for (int j = 0; j < 4; j++)
                    acc[i][j] = __builtin_amdgcn_mfma_f32_16x16x32_bf16(af[i], bfr[j], acc[i][j], 0, 0, 0);
        }
    }

    // ---- epilogue: bias, store y, fused per-channel sum/sumsq ----
    #pragma unroll
    for (int j = 0; j < 4; j++) {
        int col = wn * 64 + j * 16 + lr;
        float bv = bias[col];
        float s = 0.f, s2 = 0.f;
        #pragma unroll
        for (int i = 0; i < 4; i++) {
            int row0 = p0 + wm * 64 + i * 16 + lq * 4;
            #pragma unroll
            for (int r = 0; r < 4; r++) {
                float v = acc[i][j][r] + bv;
                y[(size_t)(row0 + r) * COUT + col] = v;
                s += v; s2 += v * v;
            }
        }
        s  += __shfl_down(s, 32);  s  += __shfl_down(s, 16);
        s2 += __shfl_down(s2, 32); s2 += __shfl_down(s2, 16);
        if (lane < 16) {
            atomicAdd(&stats[col], s);
            atomicAdd(&stats[COUT + col], s2);
        }
    }
}

// ---------------- fold BN into scale/shift ----------------
template<int COUT>
__global__ void finalize_kernel(const float* __restrict__ stats, const float* __restrict__ gamma,
                                const float* __restrict__ beta, float* __restrict__ ss, int N) {
    int co = threadIdx.x;
    float inv_n = 1.f / (float)N;
    float mu  = stats[co] * inv_n;
    float var = stats[COUT + co] * inv_n - mu * mu;
    float sc  = gamma[co] * rsqrtf(var + BN_EPS);
    ss[co]        = sc;
    ss[COUT + co] = beta[co] - mu * sc;
}

// ---------------- BN + ReLU, emit bf16 into strided (PERZ) layout ----------------
template<int COUT>
__global__ void apply_kernel(const float* __restrict__ y, const float* __restrict__ ss,
                             u16* __restrict__ f, int total4) {
    int i = blockIdx.x * blockDim.x + threadIdx.x;
    if (i >= total4) return;
    constexpr int E4 = COUT / 4;
    float4 v = ((const float4*)y)[i];
    int p = i / E4, k = i - p * E4;
    int c0 = k * 4;
    int b = p / PER, r = p - b * PER;
    ushort4 o;
    float a;
    a = fmaf(v.x, ss[c0 + 0], ss[COUT + c0 + 0]); o.x = f2b(a > 0.f ? a : 0.f);
    a = fmaf(v.y, ss[c0 + 1], ss[COUT + c0 + 1]); o.y = f2b(a > 0.f ? a : 0.f);
    a = fmaf(v.z, ss[c0 + 2], ss[COUT + c0 + 2]); o.z = f2b(a > 0.f ? a : 0.f);
    a = fmaf(v.w, ss[c0 + 3], ss[COUT + c0 + 3]); o.w = f2b(a > 0.f ? a : 0.f);
    ((ushort4*)f)[(size_t)(b * PERZ + r) * E4 + k] = o;
}

// ---------------- dense NCDHW output ----------------
__global__ void output_kernel(const u16* __restrict__ f, const int* __restrict__ map,
                              float* __restrict__ out, int total) {
    int i = blockIdx.x * blockDim.x + threadIdx.x;
    if (i >= total) return;
    int voxel = i % VOX;
    int bc    = i / VOX;
    int c = bc & 63;
    int b = bc >> 6;
    int p = map[b * VOX + voxel];
    float v = 0.f;
    if (p >= 0) {
        int r = p - b * PER;
        v = b2f(f[(size_t)(b * PERZ + r) * 64 + c]);
    }
    out[i] = v;
}

extern "C" void kernel_launch(void* const* d_in, const int* in_sizes, int n_in,
                              void* d_out, int out_size, void* d_ws, size_t ws_size,
                              hipStream_t stream) {
    const float* feats = (const float*)d_in[0];
    const int*   idx   = (const int*)  d_in[1];
    const float* W0 = (const float*)d_in[3];
    const float* b0 = (const float*)d_in[4];
    const float* g0 = (const float*)d_in[5];
    const float* e0 = (const float*)d_in[6];
    const float* W1 = (const float*)d_in[7];
    const float* b1 = (const float*)d_in[8];
    const float* g1 = (const float*)d_in[9];
    const float* e1 = (const float*)d_in[10];
    const float* W2 = (const float*)d_in[11];
    const float* b2 = (const float*)d_in[12];
    const float* g2 = (const float*)d_in[13];
    const float* e2 = (const float*)d_in[14];

    const int N = in_sizes[0] / 16;               // 442368

    // ---- workspace layout ----
    char* ws = (char*)d_ws;
    size_t off = 0;
    auto alloc = [&](size_t bytes) { void* p = ws + off; off = (off + bytes + 255) & ~(size_t)255; return p; };
    int*   map   = (int*)  alloc((size_t)BATCH * VOX * 4);
    float* stats = (float*)alloc(3 * 256 * 4);
    float* ss    = (float*)alloc(3 * 256 * 4);
    u16*   nbr   = (u16*)  alloc((size_t)N * 32 * 2);
    u16*   wt0   = (u16*)  alloc((size_t)64  * 448  * 2);
    u16*   wt1   = (u16*)  alloc((size_t)128 * 1728 * 2);
    u16*   wt2   = (u16*)  alloc((size_t)64  * 3456 * 2);
    u16*   fbuf  = (u16*)  alloc((size_t)BATCH * PERZ * 128 * 2);   // shared by all layers
    float* y = (float*)d_out;                     // fp32 conv out, aliases d_out

    hipMemsetAsync(map,   0xFF, (size_t)BATCH * VOX * 4, stream);
    hipMemsetAsync(stats, 0,    3 * 256 * 4, stream);
    hipMemsetAsync(wt0,   0,    (size_t)64 * 448 * 2, stream);      // zero K-pad
    build_map_kernel<<<(N + 255) / 256, 256, 0, stream>>>(idx, map, N);
    build_nbr_kernel<<<(N * 32 + 255) / 256, 256, 0, stream>>>(idx, map, nbr, N);
    transpose_w_kernel<<<(432  * 64  + 255) / 256, 256, 0, stream>>>(W0, wt0, 432,  64,  448);
    transpose_w_kernel<<<(1728 * 128 + 255) / 256, 256, 0, stream>>>(W1, wt1, 1728, 128, 1728);
    transpose_w_kernel<<<(3456 * 64  + 255) / 256, 256, 0, stream>>>(W2, wt2, 3456, 64,  3456);

    // ---- layer 1: 16 -> 64 (BM=256, waves 4x1) ----
    zero_rows_kernel<<<(BATCH * 4 + 255) / 256, 256, 0, stream>>>(fbuf, 16);
    cast_bf16_kernel<<<(N * 4 + 255) / 256, 256, 0, stream>>>(feats, fbuf, N * 4);
    conv_mfma_kernel<16, 64, 256, 4, 1><<<N / 256, 256, 0, stream>>>(fbuf, nbr, wt0, b0, y, stats + 0);
    finalize_kernel<64><<<1, 64, 0, stream>>>(stats + 0, g0, e0, ss + 0, N);
    zero_rows_kernel<<<(BATCH * 16 + 255) / 256, 256, 0, stream>>>(fbuf, 64);
    apply_kernel<64><<<(N * 16 + 255) / 256, 256, 0, stream>>>(y, ss + 0, fbuf, N * 16);

    // ---- layer 2: 64 -> 128 (BM=128, waves 2x2) ----
    conv_mfma_kernel<64, 128, 128, 2, 2><<<N / 128, 256, 0, stream>>>(fbuf, nbr, wt1, b1, y, stats + 256);
    finalize_kernel<128><<<1, 128, 0, stream>>>(stats + 256, g1, e1, ss + 256, N);
    zero_rows_kernel<<<(BATCH * 32 + 255) / 256, 256, 0, stream>>>(fbuf, 128);
    apply_kernel<128><<<(N * 32 + 255) / 256, 256, 0, stream>>>(y, ss + 256, fbuf, N * 32);

    // ---- layer 3: 128 -> 64 (BM=256, waves 4x1) ----
    conv_mfma_kernel<128, 64, 256, 4, 1><<<N / 256, 256, 0, stream>>>(fbuf, nbr, wt2, b2, y, stats + 512);
    finalize_kernel<64><<<1, 64, 0, stream>>>(stats + 512, g2, e2, ss + 512, N);
    zero_rows_kernel<<<(BATCH * 16 + 255) / 256, 256, 0, stream>>>(fbuf, 64);
    apply_kernel<64><<<(N * 16 + 255) / 256, 256, 0, stream>>>(y, ss + 512, fbuf, N * 16);

    // ---- dense NCDHW output ----
    output_kernel<<<(out_size + 255) / 256, 256, 0, stream>>>(fbuf, map, (float*)d_out, out_size);
}